// Round 1
// baseline (6986.012 us; speedup 1.0000x reference)
//
#include <hip/hip_runtime.h>

#define Bn 64
#define Hn 512
#define TIN 128
#define FIN 64
#define TOUTn 64
#define G4 2048  // 4*H

__device__ __forceinline__ float sig_(float x) { return 1.0f / (1.0f + __expf(-x)); }
__device__ __forceinline__ float tanh_(float x) {
    float e = __expf(2.0f * x);
    return (e - 1.0f) / (e + 1.0f);
}

__global__ __launch_bounds__(256) void init_ws(float* __restrict__ h0, float* __restrict__ c) {
    int i = blockIdx.x * 256 + threadIdx.x;
    h0[i] = 0.0f;
    c[i] = 0.0f;
}

__global__ __launch_bounds__(256) void out_init(float* __restrict__ out, const float* __restrict__ blin) {
    int i = blockIdx.x * 256 + threadIdx.x;
    out[i] = blin[i & 4095];
}

// One LSTM step (or pre2 compute), fused GEMM + activation.
// Grid: 128 blocks = 4 batch-tiles (16) x 32 hidden-tiles (16 units x 4 gate types = 64 cols).
// MODE 0: encoder step (adds x_t@Wih1^T and biases)
// MODE 1: decoder step (adds precomputed pre2; writes seq)
// MODE 2: pre2 = h1@Wih2^T + bih2 + bhh2 (raw gates, no activation)
template <int MODE>
__global__ __launch_bounds__(256) void step_kernel(
    const float* __restrict__ hin, const float* __restrict__ Wr,
    const float* __restrict__ xin, const float* __restrict__ Wx,
    const float* __restrict__ bih, const float* __restrict__ bhh,
    const float* __restrict__ pre2,
    float* __restrict__ hout, float* __restrict__ cbuf,
    float* __restrict__ seqt, float* __restrict__ pre2out)
{
    __shared__ float sA[16][17];   // batch x k chunk (padded: bank-safe)
    __shared__ float sW[64][17];   // 64 gate cols x k chunk
    __shared__ float sG[16][68];   // gate tile for activation routing

    const int tid = threadIdx.x;
    const int b0 = (blockIdx.x & 3) * 16;
    const int u0 = (blockIdx.x >> 2) * 16;
    const int cq = tid & 31;   // 32 col-pair groups
    const int bq = tid >> 5;   // 8 batch-pair groups
    float acc00 = 0.f, acc01 = 0.f, acc10 = 0.f, acc11 = 0.f;

    // ---- recurrent GEMM part: K = 512 over h ----
    for (int kk = 0; kk < Hn; kk += 16) {
        {
            int r = tid >> 4, cc = tid & 15;
            sA[r][cc] = hin[(b0 + r) * Hn + kk + cc];
        }
#pragma unroll
        for (int i = 0; i < 4; i++) {
            int idx = tid + 256 * i;
            int cl = idx >> 4, cc = idx & 15;
            sW[cl][cc] = Wr[((cl >> 4) * Hn + u0 + (cl & 15)) * Hn + kk + cc];
        }
        __syncthreads();
        float a0[16], a1[16];
#pragma unroll
        for (int kc = 0; kc < 16; kc++) { a0[kc] = sA[bq * 2][kc]; a1[kc] = sA[bq * 2 + 1][kc]; }
#pragma unroll
        for (int kc = 0; kc < 16; kc++) {
            float w0 = sW[cq * 2][kc], w1 = sW[cq * 2 + 1][kc];
            acc00 += a0[kc] * w0; acc01 += a0[kc] * w1;
            acc10 += a1[kc] * w0; acc11 += a1[kc] * w1;
        }
        __syncthreads();
    }

    // ---- encoder only: fold x_t @ Wih1^T (K = 64) ----
    if (MODE == 0) {
        for (int kk = 0; kk < FIN; kk += 16) {
            {
                int r = tid >> 4, cc = tid & 15;
                sA[r][cc] = xin[(b0 + r) * (TIN * FIN) + kk + cc];
            }
#pragma unroll
            for (int i = 0; i < 4; i++) {
                int idx = tid + 256 * i;
                int cl = idx >> 4, cc = idx & 15;
                sW[cl][cc] = Wx[((cl >> 4) * Hn + u0 + (cl & 15)) * FIN + kk + cc];
            }
            __syncthreads();
            float a0[16], a1[16];
#pragma unroll
            for (int kc = 0; kc < 16; kc++) { a0[kc] = sA[bq * 2][kc]; a1[kc] = sA[bq * 2 + 1][kc]; }
#pragma unroll
            for (int kc = 0; kc < 16; kc++) {
                float w0 = sW[cq * 2][kc], w1 = sW[cq * 2 + 1][kc];
                acc00 += a0[kc] * w0; acc01 += a0[kc] * w1;
                acc10 += a1[kc] * w0; acc11 += a1[kc] * w1;
            }
            __syncthreads();
        }
    }

    // ---- epilogue: bias / pre2 add, route gates through LDS ----
    float accs[2][2] = {{acc00, acc01}, {acc10, acc11}};
#pragma unroll
    for (int j = 0; j < 2; j++) {
        int cl = cq * 2 + j;
        int colg = (cl >> 4) * Hn + u0 + (cl & 15);
        float badd = (MODE != 1) ? (bih[colg] + bhh[colg]) : 0.0f;
#pragma unroll
        for (int i = 0; i < 2; i++) {
            float v = accs[i][j] + badd;
            if (MODE == 1) v += pre2[(b0 + bq * 2 + i) * G4 + colg];
            if (MODE == 2) pre2out[(b0 + bq * 2 + i) * G4 + colg] = v;
            else sG[bq * 2 + i][cl] = v;
        }
    }
    if (MODE == 2) return;
    __syncthreads();

    // ---- activation: 256 threads = 16 batches x 16 hidden units ----
    {
        int bl = tid >> 4, u = tid & 15;
        float gi = sG[bl][u];
        float gf = sG[bl][16 + u];
        float gg = sG[bl][32 + u];
        float go = sG[bl][48 + u];
        int idx = (b0 + bl) * Hn + u0 + u;
        float cn = sig_(gf) * cbuf[idx] + sig_(gi) * tanh_(gg);
        float hn = sig_(go) * tanh_(cn);
        cbuf[idx] = cn;
        hout[idx] = hn;
        if (MODE == 1) seqt[idx] = hn;
    }
}

// out[b, j] += sum_k seq_flat[b,k] * Wlin[j,k]; seq stored [t][b][u], k = t*512+u.
// Grid: 64 col-tiles (64 cols) x 8 k-tiles (4096) = 512 blocks. fp32 atomics for k-split.
__global__ __launch_bounds__(256) void linear_kernel(
    const float* __restrict__ seq, const float* __restrict__ Wlin, float* __restrict__ out)
{
    __shared__ __align__(16) float sA[64][20];  // 64 batches x 16 k (pad 20: float4-aligned)
    __shared__ __align__(16) float sW[64][20];  // 64 cols x 16 k
    const int tid = threadIdx.x;
    const int jt = blockIdx.x >> 3;
    const int kt = blockIdx.x & 7;
    const int j0 = jt * 64;
    const int k0 = kt * 4096;
    const int cq = tid & 15, bq = tid >> 4;
    float acc[4][4] = {};

    for (int kk = 0; kk < 4096; kk += 16) {
        int kg = k0 + kk;
        int ts = kg >> 9, uu = kg & 511;
#pragma unroll
        for (int i = 0; i < 4; i++) {
            int idx = tid + 256 * i;
            int r = idx >> 4, cc = idx & 15;
            sA[r][cc] = seq[ts * (Bn * Hn) + r * Hn + uu + cc];
            sW[r][cc] = Wlin[(size_t)(j0 + r) * 32768 + kg + cc];
        }
        __syncthreads();
#pragma unroll
        for (int k4 = 0; k4 < 16; k4 += 4) {
            float4 av[4], wv[4];
#pragma unroll
            for (int i = 0; i < 4; i++) av[i] = *(const float4*)&sA[bq * 4 + i][k4];
#pragma unroll
            for (int j = 0; j < 4; j++) wv[j] = *(const float4*)&sW[cq + 16 * j][k4];
#pragma unroll
            for (int i = 0; i < 4; i++)
#pragma unroll
                for (int j = 0; j < 4; j++)
                    acc[i][j] += av[i].x * wv[j].x + av[i].y * wv[j].y +
                                 av[i].z * wv[j].z + av[i].w * wv[j].w;
        }
        __syncthreads();
    }
#pragma unroll
    for (int i = 0; i < 4; i++)
#pragma unroll
        for (int j = 0; j < 4; j++)
            atomicAdd(&out[(bq * 4 + i) * 4096 + j0 + cq + 16 * j], acc[i][j]);
}

extern "C" void kernel_launch(void* const* d_in, const int* in_sizes, int n_in,
                              void* d_out, int out_size, void* d_ws, size_t ws_size,
                              hipStream_t stream) {
    (void)in_sizes; (void)n_in; (void)out_size; (void)ws_size;
    const float* x    = (const float*)d_in[0];
    const float* Wih1 = (const float*)d_in[1];
    const float* Whh1 = (const float*)d_in[2];
    const float* bih1 = (const float*)d_in[3];
    const float* bhh1 = (const float*)d_in[4];
    const float* Wih2 = (const float*)d_in[5];
    const float* Whh2 = (const float*)d_in[6];
    const float* bih2 = (const float*)d_in[7];
    const float* bhh2 = (const float*)d_in[8];
    const float* Wlin = (const float*)d_in[9];
    const float* blin = (const float*)d_in[10];
    float* out = (float*)d_out;
    float* ws = (float*)d_ws;

    // ws layout (floats): h0, h1, c, pre2, seq — total ~9.3 MB
    float* h0   = ws;
    float* h1   = ws + 32768;
    float* c    = ws + 65536;
    float* pre2 = ws + 98304;
    float* seq  = ws + 229376;  // 64 steps x 64 batch x 512

    init_ws<<<dim3(128), dim3(256), 0, stream>>>(h0, c);

    float* hin = h0;
    float* hout = h1;
    for (int t = 0; t < TIN; t++) {
        step_kernel<0><<<dim3(128), dim3(256), 0, stream>>>(
            hin, Whh1, x + t * FIN, Wih1, bih1, bhh1, nullptr,
            hout, c, nullptr, nullptr);
        float* tmp = hin; hin = hout; hout = tmp;
    }
    // hin now holds h1 (final encoder hidden); c holds c1.
    step_kernel<2><<<dim3(128), dim3(256), 0, stream>>>(
        hin, Wih2, nullptr, nullptr, bih2, bhh2, nullptr,
        nullptr, nullptr, nullptr, pre2);
    for (int t = 0; t < TOUTn; t++) {
        step_kernel<1><<<dim3(128), dim3(256), 0, stream>>>(
            hin, Whh2, nullptr, nullptr, nullptr, nullptr, pre2,
            hout, c, seq + (size_t)t * (Bn * Hn), nullptr);
        float* tmp = hin; hin = hout; hout = tmp;
    }
    out_init<<<dim3(1024), dim3(256), 0, stream>>>(out, blin);
    linear_kernel<<<dim3(512), dim3(256), 0, stream>>>(seq, Wlin, out);
}

// Round 2
// 2029.390 us; speedup vs baseline: 3.4424x; 3.4424x over previous
//
#include <hip/hip_runtime.h>

#define TIN 128
#define TOUT 64

// ws byte offsets
#define WS_WHH1B 0u
#define WS_WHH2B 2097152u
#define WS_WIH2B 4194304u
#define WS_WIH1B 6291456u
#define WS_XB    6553600u
#define WS_BC1   7602176u
#define WS_BC2   7610368u
#define WS_HBUF  7618560u
#define WS_SEQB  7749632u
#define WS_CNT   11943936u

typedef short short8 __attribute__((ext_vector_type(8)));
typedef short short4v __attribute__((ext_vector_type(4)));
typedef float f32x4 __attribute__((ext_vector_type(4)));

__device__ __forceinline__ f32x4 mfma16(short8 a, short8 b, f32x4 c) {
    return __builtin_amdgcn_mfma_f32_16x16x32_bf16(a, b, c, 0, 0, 0);
}
__device__ __forceinline__ short f2bf(float f) {
    unsigned u = __float_as_uint(f);
    u = (u + 0x7fffu + ((u >> 16) & 1u)) >> 16;
    return (short)u;
}
__device__ __forceinline__ float sig_(float x) { return 1.0f / (1.0f + __expf(-x)); }
__device__ __forceinline__ float tanh_(float x) {
    float e = __expf(2.0f * x);
    return (e - 1.0f) / (e + 1.0f);
}

__global__ __launch_bounds__(256) void setup_conv(
    const float* __restrict__ Whh1, const float* __restrict__ Whh2,
    const float* __restrict__ Wih2, const float* __restrict__ Wih1,
    const float* __restrict__ x,
    const float* __restrict__ bih1, const float* __restrict__ bhh1,
    const float* __restrict__ bih2, const float* __restrict__ bhh2,
    char* __restrict__ ws)
{
    int i = blockIdx.x * 256 + threadIdx.x;
    short* whh1b = (short*)(ws + WS_WHH1B);
    short* whh2b = (short*)(ws + WS_WHH2B);
    short* wih2b = (short*)(ws + WS_WIH2B);
    short* wih1b = (short*)(ws + WS_WIH1B);
    short* xb    = (short*)(ws + WS_XB);
    float* bc1   = (float*)(ws + WS_BC1);
    float* bc2   = (float*)(ws + WS_BC2);
    short* hbuf  = (short*)(ws + WS_HBUF);
    unsigned* cnt = (unsigned*)(ws + WS_CNT);
    if (i < 1048576) {
        whh1b[i] = f2bf(Whh1[i]);
        whh2b[i] = f2bf(Whh2[i]);
        wih2b[i] = f2bf(Wih2[i]);
    }
    if (i < 131072) wih1b[i] = f2bf(Wih1[i]);
    if (i < 524288) {
        // x[b][t][f] -> xb[t][b][f]
        int f = i & 63, t = (i >> 6) & 127, b = i >> 13;
        xb[(((t << 6) + b) << 6) + f] = f2bf(x[i]);
    }
    if (i < 2048) { bc1[i] = bih1[i] + bhh1[i]; bc2[i] = bih2[i] + bhh2[i]; }
    if (i < 65536) hbuf[i] = 0;
    if (i < 4) cnt[i] = 0;
}

__global__ __launch_bounds__(256) void out_init(float* __restrict__ out,
                                                const float* __restrict__ blin) {
    int i = blockIdx.x * 256 + threadIdx.x;
    out[i] = blin[i & 4095];
}

// Persistent recurrence kernel: 128 blocks = 4 batch-tiles x 32 unit-tiles.
// Block owns 16 batches x 16 hidden units (all 4 gates); wave w computes gate w.
// Whh B-fragments live in VGPRs for the whole phase; only h traverses memory.
// 4 independent barrier groups (one per batch-tile), monotonic counter barrier.
__global__ __launch_bounds__(256) void recurrence(char* __restrict__ ws) {
    const short* Whh1b = (const short*)(ws + WS_WHH1B);
    const short* Whh2b = (const short*)(ws + WS_WHH2B);
    const short* Wih2b = (const short*)(ws + WS_WIH2B);
    const short* Wih1b = (const short*)(ws + WS_WIH1B);
    const short* xb    = (const short*)(ws + WS_XB);
    const float* bc1   = (const float*)(ws + WS_BC1);
    const float* bc2   = (const float*)(ws + WS_BC2);
    short* hbuf = (short*)(ws + WS_HBUF);   // [2][64][512] bf16
    short* seqb = (short*)(ws + WS_SEQB);   // [64][32768] bf16 (b-major, k=t*512+u)
    unsigned* cnt = (unsigned*)(ws + WS_CNT);

    __shared__ __align__(16) short sH[16][520];  // h tile, padded (2-way bank = free)
    __shared__ float sG[4][16][17];              // gate exchange i,f,g,o
    __shared__ float sC[16][16];                 // cell state (block-resident all steps)

    const int tid = threadIdx.x;
    const int bt = blockIdx.x & 3;   // batch tile
    const int ut = blockIdx.x >> 2;  // unit tile 0..31
    const int w  = tid >> 6;         // wave = gate type
    const int l  = tid & 63;
    const int lo = l & 15, qu = l >> 4;

    sC[tid >> 4][tid & 15] = 0.0f;   // c0 = 0 (own slot; barrier before any read)

    const int col = w * 512 + ut * 16 + lo;  // gate column (B-frag row, bias idx)
    const float bias1 = bc1[col];
    const float bias2 = bc2[col];

    // park Whh1 + Wih1 B-fragments in registers
    short8 wf[16];
    {
        const short* r = Whh1b + (size_t)col * 512 + qu * 8;
#pragma unroll
        for (int kf = 0; kf < 16; kf++) wf[kf] = *(const short8*)(r + kf * 32);
    }
    short8 wxf0, wxf1;
    {
        const short* r = Wih1b + (size_t)col * 64 + qu * 8;
        wxf0 = *(const short8*)(r);
        wxf1 = *(const short8*)(r + 32);
    }

    const int sb = tid >> 4;    // staging: batch row
    const int scc = tid & 15;   // staging: 64-B chunk in row
    unsigned target = 0;

    // ================= encoder: 128 steps =================
    for (int t = 0; t < TIN; t++) {
        {   // stage h[t&1] tile -> sH (coalesced)
            const short* src = hbuf + (size_t)(t & 1) * 32768 + (size_t)(bt * 16 + sb) * 512 + scc * 32;
            short* dst = &sH[sb][scc * 32];
#pragma unroll
            for (int i = 0; i < 4; i++)
                *(short8*)(dst + i * 8) = *(const short8*)(src + i * 8);
        }
        const short* xsrc = xb + (((size_t)t * 64 + bt * 16 + lo) << 6) + qu * 8;
        short8 xf0 = *(const short8*)(xsrc);
        short8 xf1 = *(const short8*)(xsrc + 32);
        __syncthreads();
        f32x4 acc0 = {bias1, bias1, bias1, bias1};
        f32x4 acc1 = {0.f, 0.f, 0.f, 0.f};
#pragma unroll
        for (int kf = 0; kf < 16; kf += 2) {
            short8 a0 = *(const short8*)(&sH[lo][kf * 32] + qu * 8);
            short8 a1 = *(const short8*)(&sH[lo][(kf + 1) * 32] + qu * 8);
            acc0 = mfma16(a0, wf[kf], acc0);
            acc1 = mfma16(a1, wf[kf + 1], acc1);
        }
        acc0 = mfma16(xf0, wxf0, acc0);
        acc1 = mfma16(xf1, wxf1, acc1);
        acc0 += acc1;
#pragma unroll
        for (int r = 0; r < 4; r++) sG[w][qu * 4 + r][lo] = acc0[r];
        __syncthreads();
        {   // activation: thread = (batch, unit)
            int b = tid >> 4, u = tid & 15;
            float gi = sG[0][b][u], gf = sG[1][b][u], gg = sG[2][b][u], go = sG[3][b][u];
            float c = sig_(gf) * sC[b][u] + sig_(gi) * tanh_(gg);
            float h = sig_(go) * tanh_(c);
            sC[b][u] = c;
            hbuf[(size_t)((t + 1) & 1) * 32768 + (size_t)(bt * 16 + b) * 512 + ut * 16 + u] = f2bf(h);
        }
        __syncthreads();  // drains global stores (vmcnt 0 before s_barrier)
        target += 32;
        if (tid == 0) {
            __hip_atomic_fetch_add(&cnt[bt], 1u, __ATOMIC_RELEASE, __HIP_MEMORY_SCOPE_AGENT);
            unsigned guard = 0;
            while (__hip_atomic_load(&cnt[bt], __ATOMIC_ACQUIRE, __HIP_MEMORY_SCOPE_AGENT) < target) {
                if (++guard > (1u << 22)) break;
                __builtin_amdgcn_s_sleep(2);
            }
        }
        __syncthreads();
    }

    // ================= pre2 = h1 @ Wih2^T + bias2 (decoder input is constant) =====
    f32x4 pre;
    {
        const short* hsrc = hbuf + (size_t)(bt * 16 + lo) * 512 + qu * 8;  // h1 in buf 0
        const short* wr = Wih2b + (size_t)col * 512 + qu * 8;
        f32x4 a0 = {bias2, bias2, bias2, bias2};
        f32x4 a1 = {0.f, 0.f, 0.f, 0.f};
#pragma unroll
        for (int kf = 0; kf < 16; kf += 2) {
            a0 = mfma16(*(const short8*)(hsrc + kf * 32), *(const short8*)(wr + kf * 32), a0);
            a1 = mfma16(*(const short8*)(hsrc + (kf + 1) * 32), *(const short8*)(wr + (kf + 1) * 32), a1);
        }
        pre = a0 + a1;
    }
    {   // swap in Whh2 fragments
        const short* r = Whh2b + (size_t)col * 512 + qu * 8;
#pragma unroll
        for (int kf = 0; kf < 16; kf++) wf[kf] = *(const short8*)(r + kf * 32);
    }

    // ================= decoder: 64 steps =================
    for (int t = 0; t < TOUT; t++) {
        const int gs = TIN + t;
        {
            const short* src = hbuf + (size_t)(gs & 1) * 32768 + (size_t)(bt * 16 + sb) * 512 + scc * 32;
            short* dst = &sH[sb][scc * 32];
#pragma unroll
            for (int i = 0; i < 4; i++)
                *(short8*)(dst + i * 8) = *(const short8*)(src + i * 8);
        }
        __syncthreads();
        f32x4 acc0 = pre;
        f32x4 acc1 = {0.f, 0.f, 0.f, 0.f};
#pragma unroll
        for (int kf = 0; kf < 16; kf += 2) {
            short8 a0 = *(const short8*)(&sH[lo][kf * 32] + qu * 8);
            short8 a1 = *(const short8*)(&sH[lo][(kf + 1) * 32] + qu * 8);
            acc0 = mfma16(a0, wf[kf], acc0);
            acc1 = mfma16(a1, wf[kf + 1], acc1);
        }
        acc0 += acc1;
#pragma unroll
        for (int r = 0; r < 4; r++) sG[w][qu * 4 + r][lo] = acc0[r];
        __syncthreads();
        {
            int b = tid >> 4, u = tid & 15;
            float gi = sG[0][b][u], gf = sG[1][b][u], gg = sG[2][b][u], go = sG[3][b][u];
            float c = sig_(gf) * sC[b][u] + sig_(gi) * tanh_(gg);
            float h = sig_(go) * tanh_(c);
            sC[b][u] = c;
            short hb = f2bf(h);
            hbuf[(size_t)((gs + 1) & 1) * 32768 + (size_t)(bt * 16 + b) * 512 + ut * 16 + u] = hb;
            seqb[(size_t)(bt * 16 + b) * 32768 + t * 512 + ut * 16 + u] = hb;
        }
        __syncthreads();
        target += 32;
        if (tid == 0) {
            __hip_atomic_fetch_add(&cnt[bt], 1u, __ATOMIC_RELEASE, __HIP_MEMORY_SCOPE_AGENT);
            unsigned guard = 0;
            while (__hip_atomic_load(&cnt[bt], __ATOMIC_ACQUIRE, __HIP_MEMORY_SCOPE_AGENT) < target) {
                if (++guard > (1u << 22)) break;
                __builtin_amdgcn_s_sleep(2);
            }
        }
        __syncthreads();
    }
}

// out[b][j] += sum_k seqb[b][k] * bf16(Wlin[j][k]); 256 blocks = 64 j-tiles x 4 k-splits.
// Wlin streamed fp32 (read exactly once: HBM floor 81 us), converted to bf16 in LDS,
// double-buffered; seq A-fragments straight from global (L2/LLC-resident, 4 MB).
__global__ __launch_bounds__(256) void linear2(const float* __restrict__ Wlin,
                                               const char* __restrict__ ws,
                                               float* __restrict__ out) {
    const short* seqb = (const short*)(ws + WS_SEQB);
    __shared__ __align__(16) short sW[2][64][72];  // [buf][j][k] bf16, +8 pad

    const int tid = threadIdx.x;
    const int jt = blockIdx.x & 63;
    const int ks = blockIdx.x >> 6;
    const int j0 = jt * 64;
    const size_t k0 = (size_t)ks * 8192;
    const int l = tid & 63, lo = l & 15, qu = l >> 4;
    const int m0 = (tid >> 6) * 16;  // wave = batch tile

    const int sj = tid >> 2;   // staging row 0..63
    const int sc4 = tid & 3;   // 4 threads/row, 256B contiguous per row/iter

    f32x4 acc[4] = {{0.f,0.f,0.f,0.f},{0.f,0.f,0.f,0.f},{0.f,0.f,0.f,0.f},{0.f,0.f,0.f,0.f}};

    float4 ld[4];
    const float* wbase = Wlin + (size_t)(j0 + sj) * 32768 + k0 + sc4 * 4;
    // prologue: tile 0
#pragma unroll
    for (int i = 0; i < 4; i++) ld[i] = *(const float4*)(wbase + i * 16);
#pragma unroll
    for (int i = 0; i < 4; i++) {
        short4v v = {f2bf(ld[i].x), f2bf(ld[i].y), f2bf(ld[i].z), f2bf(ld[i].w)};
        *(short4v*)(&sW[0][sj][sc4 * 4 + i * 16]) = v;
    }
    __syncthreads();

    for (int it = 0; it < 128; it++) {
        const int cur = it & 1;
        if (it + 1 < 128) {
            const float* p = wbase + (size_t)(it + 1) * 64;
#pragma unroll
            for (int i = 0; i < 4; i++) ld[i] = *(const float4*)(p + i * 16);
        }
        // compute: 2 k-chunks of 32
        const short* arow = seqb + (size_t)(m0 + lo) * 32768 + k0 + (size_t)it * 64 + qu * 8;
        short8 a0 = *(const short8*)(arow);
        short8 a1 = *(const short8*)(arow + 32);
#pragma unroll
        for (int nt = 0; nt < 4; nt++) {
            short8 b0 = *(const short8*)(&sW[cur][nt * 16 + lo][qu * 8]);
            short8 b1 = *(const short8*)(&sW[cur][nt * 16 + lo][32 + qu * 8]);
            acc[nt] = mfma16(a0, b0, acc[nt]);
            acc[nt] = mfma16(a1, b1, acc[nt]);
        }
        __syncthreads();
        if (it + 1 < 128) {
#pragma unroll
            for (int i = 0; i < 4; i++) {
                short4v v = {f2bf(ld[i].x), f2bf(ld[i].y), f2bf(ld[i].z), f2bf(ld[i].w)};
                *(short4v*)(&sW[cur ^ 1][sj][sc4 * 4 + i * 16]) = v;
            }
        }
        __syncthreads();
    }
#pragma unroll
    for (int nt = 0; nt < 4; nt++)
#pragma unroll
        for (int r = 0; r < 4; r++)
            atomicAdd(out + (size_t)(m0 + qu * 4 + r) * 4096 + j0 + nt * 16 + lo, acc[nt][r]);
}

extern "C" void kernel_launch(void* const* d_in, const int* in_sizes, int n_in,
                              void* d_out, int out_size, void* d_ws, size_t ws_size,
                              hipStream_t stream) {
    (void)in_sizes; (void)n_in; (void)out_size; (void)ws_size;
    const float* x    = (const float*)d_in[0];
    const float* Wih1 = (const float*)d_in[1];
    const float* Whh1 = (const float*)d_in[2];
    const float* bih1 = (const float*)d_in[3];
    const float* bhh1 = (const float*)d_in[4];
    const float* Wih2 = (const float*)d_in[5];
    const float* Whh2 = (const float*)d_in[6];
    const float* bih2 = (const float*)d_in[7];
    const float* bhh2 = (const float*)d_in[8];
    const float* Wlin = (const float*)d_in[9];
    const float* blin = (const float*)d_in[10];
    float* out = (float*)d_out;
    char* ws = (char*)d_ws;

    setup_conv<<<dim3(4096), dim3(256), 0, stream>>>(Whh1, Whh2, Wih2, Wih1, x,
                                                     bih1, bhh1, bih2, bhh2, ws);
    recurrence<<<dim3(128), dim3(256), 0, stream>>>(ws);
    out_init<<<dim3(1024), dim3(256), 0, stream>>>(out, blin);
    linear2<<<dim3(256), dim3(256), 0, stream>>>(Wlin, ws, out);
}

// Round 4
// 1236.496 us; speedup vs baseline: 5.6498x; 1.6412x over previous
//
#include <hip/hip_runtime.h>

#define TIN 128
#define TOUT 64

// ws byte offsets
#define WS_WHH1B 0u
#define WS_WHH2B 2097152u
#define WS_WIH2B 4194304u
#define WS_WIH1B 6291456u
#define WS_XB    6553600u
#define WS_BC1   7602176u
#define WS_BC2   7610368u
#define WS_HBUF  7618560u      // 2*64*512 bf16 = 131072 B
#define WS_SEQB  7749632u      // 64*32768 bf16 = 4 MB
#define WS_FLAGS 11943936u     // 128 uints

typedef short short8 __attribute__((ext_vector_type(8)));
typedef float f32x4 __attribute__((ext_vector_type(4)));
typedef unsigned long long ull;

__device__ __forceinline__ f32x4 mfma16(short8 a, short8 b, f32x4 c) {
    return __builtin_amdgcn_mfma_f32_16x16x32_bf16(a, b, c, 0, 0, 0);
}
__device__ __forceinline__ short f2bf(float f) {
    unsigned u = __float_as_uint(f);
    u = (u + 0x7fffu + ((u >> 16) & 1u)) >> 16;
    return (short)u;
}
__device__ __forceinline__ float sig_(float x) { return 1.0f / (1.0f + __expf(-x)); }
__device__ __forceinline__ float tanh_(float x) {
    float e = __expf(2.0f * x);
    return (e - 1.0f) / (e + 1.0f);
}

__global__ __launch_bounds__(256) void setup_conv(
    const float* __restrict__ Whh1, const float* __restrict__ Whh2,
    const float* __restrict__ Wih2, const float* __restrict__ Wih1,
    const float* __restrict__ x,
    const float* __restrict__ bih1, const float* __restrict__ bhh1,
    const float* __restrict__ bih2, const float* __restrict__ bhh2,
    char* __restrict__ ws)
{
    int i = blockIdx.x * 256 + threadIdx.x;
    short* whh1b = (short*)(ws + WS_WHH1B);
    short* whh2b = (short*)(ws + WS_WHH2B);
    short* wih2b = (short*)(ws + WS_WIH2B);
    short* wih1b = (short*)(ws + WS_WIH1B);
    short* xb    = (short*)(ws + WS_XB);
    float* bc1   = (float*)(ws + WS_BC1);
    float* bc2   = (float*)(ws + WS_BC2);
    short* hbuf  = (short*)(ws + WS_HBUF);
    unsigned* flags = (unsigned*)(ws + WS_FLAGS);
    if (i < 1048576) {
        whh1b[i] = f2bf(Whh1[i]);
        whh2b[i] = f2bf(Whh2[i]);
        wih2b[i] = f2bf(Wih2[i]);
    }
    if (i < 131072) wih1b[i] = f2bf(Wih1[i]);
    if (i < 524288) {
        // x[b][t][f] -> xb[t][b][f]
        int f = i & 63, t = (i >> 6) & 127, b = i >> 13;
        xb[(((t << 6) + b) << 6) + f] = f2bf(x[i]);
    }
    if (i < 2048) { bc1[i] = bih1[i] + bhh1[i]; bc2[i] = bih2[i] + bhh2[i]; }
    if (i < 65536) hbuf[i] = 0;
    if (i < 128) flags[i] = 0;
}

__global__ __launch_bounds__(256) void out_init(float* __restrict__ out,
                                                const float* __restrict__ blin) {
    int i = blockIdx.x * 256 + threadIdx.x;
    out[i] = blin[i & 4095];
}

// Persistent recurrence: 128 blocks = 4 batch-groups x 32 unit-tiles.
// Cross-block traffic via relaxed agent-scope atomics (sc1: act at LLC, no
// buffer_inv/wbl2 storms, no RMW serialization). Producer ordering: data
// stores -> __syncthreads (vmcnt(0) drain, stores at coherence point) -> flag.
__global__ __launch_bounds__(256) void recurrence(char* __restrict__ ws) {
    const short* Whh1b = (const short*)(ws + WS_WHH1B);
    const short* Whh2b = (const short*)(ws + WS_WHH2B);
    const short* Wih2b = (const short*)(ws + WS_WIH2B);
    const short* Wih1b = (const short*)(ws + WS_WIH1B);
    const short* xb    = (const short*)(ws + WS_XB);
    const float* bc1   = (const float*)(ws + WS_BC1);
    const float* bc2   = (const float*)(ws + WS_BC2);
    short* hbuf = (short*)(ws + WS_HBUF);   // [2][64][512] bf16
    short* seqb = (short*)(ws + WS_SEQB);   // [64][32768] bf16
    unsigned* flags = (unsigned*)(ws + WS_FLAGS);

    __shared__ __align__(16) short sH[16][520];
    __shared__ float sG[4][16][17];
    __shared__ float sC[16][16];

    const int tid = threadIdx.x;
    const int bt = blockIdx.x & 3;
    const int ut = blockIdx.x >> 2;
    const int w  = tid >> 6;
    const int l  = tid & 63;
    const int lo = l & 15, qu = l >> 4;

    sC[tid >> 4][tid & 15] = 0.0f;

    const int col = w * 512 + ut * 16 + lo;
    const float bias1 = bc1[col];
    const float bias2 = bc2[col];

    short8 wf[16];
    {
        const short* r = Whh1b + (size_t)col * 512 + qu * 8;
#pragma unroll
        for (int kf = 0; kf < 16; kf++) wf[kf] = *(const short8*)(r + kf * 32);
    }
    short8 wxf0, wxf1;
    {
        const short* r = Wih1b + (size_t)col * 64 + qu * 8;
        wxf0 = *(const short8*)(r);
        wxf1 = *(const short8*)(r + 32);
    }

    const int srow = tid >> 4;   // staging row 0..15
    const int schk = tid & 15;   // staging 64-B chunk (8 ulls) in 1024-B row
    unsigned* myflag = flags + bt * 32 + ut;
    unsigned* pollflag = flags + bt * 32 + (tid & 31);

#define ATOM_LD(p) __hip_atomic_load((p), __ATOMIC_RELAXED, __HIP_MEMORY_SCOPE_AGENT)

// Full row copy: 16 threads/row x 64 B/thread = 1024 B = 512 bf16. (Round-3 bug
// was 32 B/thread here -> half of sH uninitialized -> MFMA inf -> tanh NaN.)
#define STAGE_H(bufidx)                                                          \
    {                                                                            \
        const ull* src = (const ull*)(hbuf + (size_t)(bufidx) * 32768 +          \
                                      (size_t)(bt * 16 + srow) * 512) + schk * 8;\
        ull* dst = (ull*)(&sH[srow][schk * 32]);                                 \
        ull v0 = ATOM_LD(src + 0); ull v1 = ATOM_LD(src + 1);                    \
        ull v2 = ATOM_LD(src + 2); ull v3 = ATOM_LD(src + 3);                    \
        ull v4 = ATOM_LD(src + 4); ull v5 = ATOM_LD(src + 5);                    \
        ull v6 = ATOM_LD(src + 6); ull v7 = ATOM_LD(src + 7);                    \
        dst[0] = v0; dst[1] = v1; dst[2] = v2; dst[3] = v3;                      \
        dst[4] = v4; dst[5] = v5; dst[6] = v6; dst[7] = v7;                      \
    }

#define FLAG_AND_POLL(stepv)                                                     \
    {                                                                            \
        if (tid == 0)                                                            \
            __hip_atomic_store(myflag, (stepv), __ATOMIC_RELAXED, __HIP_MEMORY_SCOPE_AGENT); \
        if (tid < 64) {                                                          \
            int guard = 0;                                                       \
            while (true) {                                                       \
                unsigned v = ATOM_LD(pollflag);                                  \
                if (__all((int)(v >= (stepv)))) break;                           \
                if (++guard > (1 << 22)) break;                                  \
            }                                                                    \
        }                                                                        \
        __syncthreads();                                                         \
    }

    // ================= encoder: 128 steps =================
    for (int t = 0; t < TIN; t++) {
        STAGE_H(t & 1);
        const short* xsrc = xb + (((size_t)t * 64 + bt * 16 + lo) << 6) + qu * 8;
        short8 xf0 = *(const short8*)(xsrc);
        short8 xf1 = *(const short8*)(xsrc + 32);
        __syncthreads();
        f32x4 acc0 = {bias1, bias1, bias1, bias1};
        f32x4 acc1 = {0.f, 0.f, 0.f, 0.f};
#pragma unroll
        for (int kf = 0; kf < 16; kf += 2) {
            short8 a0 = *(const short8*)(&sH[lo][kf * 32] + qu * 8);
            short8 a1 = *(const short8*)(&sH[lo][(kf + 1) * 32] + qu * 8);
            acc0 = mfma16(a0, wf[kf], acc0);
            acc1 = mfma16(a1, wf[kf + 1], acc1);
        }
        acc0 = mfma16(xf0, wxf0, acc0);
        acc1 = mfma16(xf1, wxf1, acc1);
        acc0 += acc1;
#pragma unroll
        for (int r = 0; r < 4; r++) sG[w][qu * 4 + r][lo] = acc0[r];
        __syncthreads();
        {
            int b = tid >> 4, u = tid & 15;
            float gi = sG[0][b][u], gf = sG[1][b][u], gg = sG[2][b][u], go = sG[3][b][u];
            float c = sig_(gf) * sC[b][u] + sig_(gi) * tanh_(gg);
            float h = sig_(go) * tanh_(c);
            sC[b][u] = c;
            unsigned hb = (unsigned)(unsigned short)f2bf(h);
            unsigned other = (unsigned)__shfl_xor((int)hb, 1);
            if ((u & 1) == 0) {
                unsigned word = hb | (other << 16);
                size_t off = (size_t)((t + 1) & 1) * 32768 + (size_t)(bt * 16 + b) * 512 + ut * 16 + u;
                __hip_atomic_store((unsigned*)(hbuf + off), word, __ATOMIC_RELAXED, __HIP_MEMORY_SCOPE_AGENT);
            }
        }
        __syncthreads();  // vmcnt(0) drain: h stores at LLC before flag store
        FLAG_AND_POLL((unsigned)(t + 1));
    }

    // ===== pre2 = h1 @ Wih2^T + bias2 (h1 in hbuf[0]) =====
    f32x4 pre;
    STAGE_H(0);
    __syncthreads();
    {
        const short* wr = Wih2b + (size_t)col * 512 + qu * 8;
        f32x4 a0 = {bias2, bias2, bias2, bias2};
        f32x4 a1 = {0.f, 0.f, 0.f, 0.f};
#pragma unroll
        for (int kf = 0; kf < 16; kf += 2) {
            short8 h0 = *(const short8*)(&sH[lo][kf * 32] + qu * 8);
            short8 h1 = *(const short8*)(&sH[lo][(kf + 1) * 32] + qu * 8);
            a0 = mfma16(h0, *(const short8*)(wr + kf * 32), a0);
            a1 = mfma16(h1, *(const short8*)(wr + (kf + 1) * 32), a1);
        }
        pre = a0 + a1;
    }
    {
        const short* r = Whh2b + (size_t)col * 512 + qu * 8;
#pragma unroll
        for (int kf = 0; kf < 16; kf++) wf[kf] = *(const short8*)(r + kf * 32);
    }
    __syncthreads();  // sH reads done before decoder restages

    // ================= decoder: 64 steps =================
    for (int t = 0; t < TOUT; t++) {
        const int gs = TIN + t;
        STAGE_H(gs & 1);
        __syncthreads();
        f32x4 acc0 = pre;
        f32x4 acc1 = {0.f, 0.f, 0.f, 0.f};
#pragma unroll
        for (int kf = 0; kf < 16; kf += 2) {
            short8 a0 = *(const short8*)(&sH[lo][kf * 32] + qu * 8);
            short8 a1 = *(const short8*)(&sH[lo][(kf + 1) * 32] + qu * 8);
            acc0 = mfma16(a0, wf[kf], acc0);
            acc1 = mfma16(a1, wf[kf + 1], acc1);
        }
        acc0 += acc1;
#pragma unroll
        for (int r = 0; r < 4; r++) sG[w][qu * 4 + r][lo] = acc0[r];
        __syncthreads();
        {
            int b = tid >> 4, u = tid & 15;
            float gi = sG[0][b][u], gf = sG[1][b][u], gg = sG[2][b][u], go = sG[3][b][u];
            float c = sig_(gf) * sC[b][u] + sig_(gi) * tanh_(gg);
            float h = sig_(go) * tanh_(c);
            sC[b][u] = c;
            unsigned hb = (unsigned)(unsigned short)f2bf(h);
            unsigned other = (unsigned)__shfl_xor((int)hb, 1);
            if ((u & 1) == 0) {
                unsigned word = hb | (other << 16);
                size_t off = (size_t)((gs + 1) & 1) * 32768 + (size_t)(bt * 16 + b) * 512 + ut * 16 + u;
                __hip_atomic_store((unsigned*)(hbuf + off), word, __ATOMIC_RELAXED, __HIP_MEMORY_SCOPE_AGENT);
                size_t soff = (size_t)(bt * 16 + b) * 32768 + (size_t)t * 512 + ut * 16 + u;
                *(unsigned*)(seqb + soff) = word;  // cross-kernel: flushed at dispatch end
            }
        }
        __syncthreads();
        if (t < TOUT - 1) {
            FLAG_AND_POLL((unsigned)(gs + 1));
        }
    }
#undef STAGE_H
#undef FLAG_AND_POLL
#undef ATOM_LD
}

// out[b][j] += seq[b][:] . Wlin[j][:]. Grid: 512 = 64 j-groups x 8 k-splits,
// 2 blocks/CU. B (the 512 MB stream) fp32->bf16 converted in registers, no LDS.
// A (seq, 4 MB LLC-hot) staged once per block per K=128 chunk, double-buffered.
__global__ __launch_bounds__(256) void linear2(const float* __restrict__ Wlin,
                                               const char* __restrict__ ws,
                                               float* __restrict__ out) {
    const short* seqb = (const short*)(ws + WS_SEQB);
    __shared__ __align__(16) short sA[2][64][136];

    const int tid = threadIdx.x;
    const int jb = blockIdx.x & 63;
    const int ks = blockIdx.x >> 6;
    const int jg = jb * 64;
    const int kbase = ks * 4096;
    const int w = tid >> 6, l = tid & 63, lo = l & 15, qu = l >> 4;
    const int jrow = jg + w * 16 + lo;
    const float* wp0 = Wlin + (size_t)jrow * 32768 + kbase + qu * 8;

    f32x4 acc[4] = {{0.f,0.f,0.f,0.f},{0.f,0.f,0.f,0.f},{0.f,0.f,0.f,0.f},{0.f,0.f,0.f,0.f}};

    short8 areg[4];
    // prologue: stage A chunk 0
#pragma unroll
    for (int i = 0; i < 4; i++) {
        int idx = tid + 256 * i;
        int row = idx >> 4, c8 = idx & 15;
        areg[i] = *(const short8*)(seqb + (size_t)row * 32768 + kbase + c8 * 8);
    }
#pragma unroll
    for (int i = 0; i < 4; i++) {
        int idx = tid + 256 * i;
        int row = idx >> 4, c8 = idx & 15;
        *(short8*)(&sA[0][row][c8 * 8]) = areg[i];
    }
    __syncthreads();

    for (int it = 0; it < 32; it++) {
        const int cur = it & 1;
        if (it < 31) {
#pragma unroll
            for (int i = 0; i < 4; i++) {
                int idx = tid + 256 * i;
                int row = idx >> 4, c8 = idx & 15;
                areg[i] = *(const short8*)(seqb + (size_t)row * 32768 + kbase + (it + 1) * 128 + c8 * 8);
            }
        }
        const float* wp = wp0 + it * 128;
#pragma unroll
        for (int c = 0; c < 4; c++) {
            float4 b0 = *(const float4*)(wp + c * 32);
            float4 b1 = *(const float4*)(wp + c * 32 + 4);
            short8 bf = {f2bf(b0.x), f2bf(b0.y), f2bf(b0.z), f2bf(b0.w),
                         f2bf(b1.x), f2bf(b1.y), f2bf(b1.z), f2bf(b1.w)};
#pragma unroll
            for (int mt = 0; mt < 4; mt++) {
                short8 af = *(const short8*)(&sA[cur][mt * 16 + lo][c * 32 + qu * 8]);
                acc[mt] = mfma16(af, bf, acc[mt]);
            }
        }
        if (it < 31) {
#pragma unroll
            for (int i = 0; i < 4; i++) {
                int idx = tid + 256 * i;
                int row = idx >> 4, c8 = idx & 15;
                *(short8*)(&sA[cur ^ 1][row][c8 * 8]) = areg[i];
            }
        }
        __syncthreads();
    }
#pragma unroll
    for (int mt = 0; mt < 4; mt++)
#pragma unroll
        for (int r = 0; r < 4; r++)
            atomicAdd(out + (size_t)(mt * 16 + qu * 4 + r) * 4096 + jrow, acc[mt][r]);
}

extern "C" void kernel_launch(void* const* d_in, const int* in_sizes, int n_in,
                              void* d_out, int out_size, void* d_ws, size_t ws_size,
                              hipStream_t stream) {
    (void)in_sizes; (void)n_in; (void)out_size; (void)ws_size;
    const float* x    = (const float*)d_in[0];
    const float* Wih1 = (const float*)d_in[1];
    const float* Whh1 = (const float*)d_in[2];
    const float* bih1 = (const float*)d_in[3];
    const float* bhh1 = (const float*)d_in[4];
    const float* Wih2 = (const float*)d_in[5];
    const float* Whh2 = (const float*)d_in[6];
    const float* bih2 = (const float*)d_in[7];
    const float* bhh2 = (const float*)d_in[8];
    const float* Wlin = (const float*)d_in[9];
    const float* blin = (const float*)d_in[10];
    float* out = (float*)d_out;
    char* ws = (char*)d_ws;

    setup_conv<<<dim3(4096), dim3(256), 0, stream>>>(Whh1, Whh2, Wih2, Wih1, x,
                                                     bih1, bhh1, bih2, bhh2, ws);
    recurrence<<<dim3(128), dim3(256), 0, stream>>>(ws);
    out_init<<<dim3(1024), dim3(256), 0, stream>>>(out, blin);
    linear2<<<dim3(512), dim3(256), 0, stream>>>(Wlin, ws, out);
}